// Round 7
// baseline (44024.673 us; speedup 1.0000x reference)
//
#include <hip/hip_runtime.h>

typedef _Float16 half8 __attribute__((ext_vector_type(8)));
typedef _Float16 half4 __attribute__((ext_vector_type(4)));
typedef float floatx4 __attribute__((ext_vector_type(4)));
typedef unsigned int uintx4 __attribute__((ext_vector_type(4)));

#define CCH 256
#define LSEQ 8192
#define TOUT 112                 // output rows per block
#define SROWS 128                // staged rows = TOUT + 4*RB
#define HALO 8                   // halo each side
#define RB 4                     // resblocks fused per launch
#define NTILES 74                // ceil(8192/112)
#define ROWB 512
#define R1OFF (SROWS * ROWB)     // 65536
#define LDSB (2 * SROWS * ROWB)  // 131072

__device__ __forceinline__ int swz(int row, int byte) {
  return row * ROWB + (byte ^ ((row & 7) << 4));
}
__device__ __forceinline__ floatx4 zero4() {
  floatx4 v; v[0] = 0.f; v[1] = 0.f; v[2] = 0.f; v[3] = 0.f; return v;
}
__device__ __forceinline__ int clampr(int r) {
  return r < 0 ? 0 : (r > SROWS - 1 ? SROWS - 1 : r);
}

// MODE 0: 4 fused resblocks, LDS-resident state, h carried f32 in registers.
//   conv2 accumulates directly into hreg via pre-scale trick:
//     t = h*rs2 + tsh  (rs2 = 1/(0.15*s2), tsh = 0.15*sh2*rs2)
//     hreg = mfma(..., t);  y = hreg * sc2p  (sc2p = 0.15*s2)
//   -> eliminates the 32-reg acc2 array.
// MODE 1: single conv + affine + relu (up_block1).
// Register control: launch_bounds' 2nd arg is only a MIN (R2-R6 evidence:
// allocator targets 8 waves/EU -> 64 VGPR -> massive spill). amdgpu_waves_per_eu
// with max=4 caps occupancy at what LDS already dictates (1 blk/CU = 4 waves/EU),
// giving the allocator a 128-VGPR budget.
template <int MODE>
__global__ __attribute__((amdgpu_flat_work_group_size(1024, 1024), amdgpu_waves_per_eu(4, 4)))
void fused4(
    const _Float16* __restrict__ src, _Float16* __restrict__ dst,
    const _Float16* __restrict__ wA, const _Float16* __restrict__ wB,
    const float* __restrict__ sc1v, const float* __restrict__ sh1v,
    const float* __restrict__ sc2pv, const float* __restrict__ rs2v,
    const float* __restrict__ tshv) {
  __shared__ __align__(16) char smem[LDSB];
  const int t = threadIdx.x;
  const int bx = blockIdx.x;
  const int b = bx / NTILES;
  const int tile = bx - b * NTILES;
  const int l0 = tile * TOUT - HALO;  // l of buffer row 0

  // ---- stage SROWS x 512B (f16) into swizzled LDS h-buffer
  for (int c = t; c < SROWS * 32; c += 1024) {
    const int row = c >> 5, col = c & 31;
    const int l = l0 + row;
    uintx4 v = {0u, 0u, 0u, 0u};
    if (l >= 0 && l < LSEQ)
      v = *(const uintx4*)(src + (((size_t)b * LSEQ + l) << 8) + col * 8);
    *(uintx4*)(smem + swz(row, col * 16)) = v;
  }
  __syncthreads();

  const int w = t >> 6, ln = t & 63;
  const int cg = w >> 2, lgrp = w & 3;   // co-group 0..3, l-group 0..3
  const int lrow = ln & 15, kgrp = ln >> 4;

  if constexpr (MODE == 0) {
    // h in f32 registers for exact residual accumulation (all 128 rows covered)
    floatx4 hreg[4][2];
#pragma unroll
    for (int i = 0; i < 4; ++i)
#pragma unroll
      for (int j = 0; j < 2; ++j) {
        const int v = (lgrp * 2 + j) * 16 + lrow;
        const int cb = (cg * 64 + i * 16 + kgrp * 4) * 2;
        half4 h = *(const half4*)(smem + swz(v, cb));
        hreg[i][j][0] = (float)h[0]; hreg[i][j][1] = (float)h[1];
        hreg[i][j][2] = (float)h[2]; hreg[i][j][3] = (float)h[3];
      }

    for (int rb = 0; rb < RB; ++rb) {
      // ---- conv1: full-width (halo garbage creeps 2 rows/side per rb, within HALO)
      floatx4 acc[4][2];
#pragma unroll
      for (int i = 0; i < 4; ++i)
#pragma unroll
        for (int j = 0; j < 2; ++j) acc[i][j] = zero4();
      for (int tap = 0; tap < 3; ++tap) {
        for (int kc = 0; kc < 8; ++kc) {
          const _Float16* wp = wA + ((size_t)(tap * CCH + cg * 64 + lrow) * CCH) + kc * 32 + kgrp * 8;
          half8 a0 = *(const half8*)(wp);
          half8 a1 = *(const half8*)(wp + 16 * CCH);
          half8 a2 = *(const half8*)(wp + 32 * CCH);
          half8 a3 = *(const half8*)(wp + 48 * CCH);
          const int byt = kc * 64 + kgrp * 16;
#pragma unroll
          for (int j = 0; j < 2; ++j) {
            const int brow = clampr((lgrp * 2 + j) * 16 + lrow + tap - 1);
            half8 bf = *(const half8*)(smem + swz(brow, byt));
            acc[0][j] = __builtin_amdgcn_mfma_f32_16x16x32_f16(a0, bf, acc[0][j], 0, 0, 0);
            acc[1][j] = __builtin_amdgcn_mfma_f32_16x16x32_f16(a1, bf, acc[1][j], 0, 0, 0);
            acc[2][j] = __builtin_amdgcn_mfma_f32_16x16x32_f16(a2, bf, acc[2][j], 0, 0, 0);
            acc[3][j] = __builtin_amdgcn_mfma_f32_16x16x32_f16(a3, bf, acc[3][j], 0, 0, 0);
          }
        }
      }
      // epilogue 1: bn1+relu -> r1 (f16), zero outside sequence
#pragma unroll
      for (int i = 0; i < 4; ++i) {
        const int co = cg * 64 + i * 16 + kgrp * 4;
        floatx4 s = *(const floatx4*)(sc1v + co);
        floatx4 sh = *(const floatx4*)(sh1v + co);
#pragma unroll
        for (int j = 0; j < 2; ++j) {
          const int v = (lgrp * 2 + j) * 16 + lrow;
          const int l = l0 + v;
          const bool valid = (l >= 0) && (l < LSEQ);
          unsigned long long pk = 0;
#pragma unroll
          for (int r = 0; r < 4; ++r) {
            float y = acc[i][j][r] * s[r] + sh[r];
            y = valid ? fmaxf(y, 0.f) : 0.f;
            unsigned short u = __builtin_bit_cast(unsigned short, (_Float16)y);
            pk |= (unsigned long long)u << (16 * r);
          }
          *(unsigned long long*)(smem + R1OFF + swz(v, co * 2)) = pk;
        }
      }
      // ---- transform hreg into conv2-accumulator domain: t = h*rs2 + tsh
#pragma unroll
      for (int i = 0; i < 4; ++i) {
        const int co = cg * 64 + i * 16 + kgrp * 4;
        floatx4 rs = *(const floatx4*)(rs2v + co);
        floatx4 ts = *(const floatx4*)(tshv + co);
#pragma unroll
        for (int j = 0; j < 2; ++j)
#pragma unroll
          for (int r = 0; r < 4; ++r)
            hreg[i][j][r] = hreg[i][j][r] * rs[r] + ts[r];
      }
      __syncthreads();
      // ---- conv2 over r1, accumulating into hreg (no acc2 array)
      for (int tap = 0; tap < 3; ++tap) {
        for (int kc = 0; kc < 8; ++kc) {
          const _Float16* wp = wB + ((size_t)(tap * CCH + cg * 64 + lrow) * CCH) + kc * 32 + kgrp * 8;
          half8 a0 = *(const half8*)(wp);
          half8 a1 = *(const half8*)(wp + 16 * CCH);
          half8 a2 = *(const half8*)(wp + 32 * CCH);
          half8 a3 = *(const half8*)(wp + 48 * CCH);
          const int byt = kc * 64 + kgrp * 16;
#pragma unroll
          for (int j = 0; j < 2; ++j) {
            const int brow = clampr((lgrp * 2 + j) * 16 + lrow + tap - 1);
            half8 bf = *(const half8*)(smem + R1OFF + swz(brow, byt));
            hreg[0][j] = __builtin_amdgcn_mfma_f32_16x16x32_f16(a0, bf, hreg[0][j], 0, 0, 0);
            hreg[1][j] = __builtin_amdgcn_mfma_f32_16x16x32_f16(a1, bf, hreg[1][j], 0, 0, 0);
            hreg[2][j] = __builtin_amdgcn_mfma_f32_16x16x32_f16(a2, bf, hreg[2][j], 0, 0, 0);
            hreg[3][j] = __builtin_amdgcn_mfma_f32_16x16x32_f16(a3, bf, hreg[3][j], 0, 0, 0);
          }
        }
      }
      // epilogue 2: y = hreg * sc2p; pin OOS rows to 0; refresh LDS h (f16)
#pragma unroll
      for (int i = 0; i < 4; ++i) {
        const int co = cg * 64 + i * 16 + kgrp * 4;
        floatx4 sp = *(const floatx4*)(sc2pv + co);
#pragma unroll
        for (int j = 0; j < 2; ++j) {
          const int v = (lgrp * 2 + j) * 16 + lrow;
          const int l = l0 + v;
          const bool valid = (l >= 0) && (l < LSEQ);
          unsigned long long pk = 0;
#pragma unroll
          for (int r = 0; r < 4; ++r) {
            float y = valid ? (hreg[i][j][r] * sp[r]) : 0.f;
            hreg[i][j][r] = y;
            unsigned short u = __builtin_bit_cast(unsigned short, (_Float16)y);
            pk |= (unsigned long long)u << (16 * r);
          }
          *(unsigned long long*)(smem + swz(v, co * 2)) = pk;
        }
      }
      __syncthreads();
    }
    // ---- write own output rows [HALO, HALO+TOUT) from f32 registers
#pragma unroll
    for (int i = 0; i < 4; ++i) {
      const int co = cg * 64 + i * 16 + kgrp * 4;
#pragma unroll
      for (int j = 0; j < 2; ++j) {
        const int v = (lgrp * 2 + j) * 16 + lrow;
        const int l = l0 + v;
        if (v >= HALO && v < HALO + TOUT && l < LSEQ) {
          half4 h;
          h[0] = (_Float16)hreg[i][j][0]; h[1] = (_Float16)hreg[i][j][1];
          h[2] = (_Float16)hreg[i][j][2]; h[3] = (_Float16)hreg[i][j][3];
          *(half4*)(dst + (((size_t)b * LSEQ + l) << 8) + co) = h;
        }
      }
    }
  } else {
    // MODE 1: out = relu(conv(h)*sc + sh), own rows only
    floatx4 acc[4][2];
#pragma unroll
    for (int i = 0; i < 4; ++i)
#pragma unroll
      for (int j = 0; j < 2; ++j) acc[i][j] = zero4();
    for (int tap = 0; tap < 3; ++tap) {
      for (int kc = 0; kc < 8; ++kc) {
        const _Float16* wp = wA + ((size_t)(tap * CCH + cg * 64 + lrow) * CCH) + kc * 32 + kgrp * 8;
        half8 a0 = *(const half8*)(wp);
        half8 a1 = *(const half8*)(wp + 16 * CCH);
        half8 a2 = *(const half8*)(wp + 32 * CCH);
        half8 a3 = *(const half8*)(wp + 48 * CCH);
        const int byt = kc * 64 + kgrp * 16;
#pragma unroll
        for (int j = 0; j < 2; ++j) {
          const int brow = clampr((lgrp * 2 + j) * 16 + lrow + tap - 1);
          half8 bf = *(const half8*)(smem + swz(brow, byt));
          acc[0][j] = __builtin_amdgcn_mfma_f32_16x16x32_f16(a0, bf, acc[0][j], 0, 0, 0);
          acc[1][j] = __builtin_amdgcn_mfma_f32_16x16x32_f16(a1, bf, acc[1][j], 0, 0, 0);
          acc[2][j] = __builtin_amdgcn_mfma_f32_16x16x32_f16(a2, bf, acc[2][j], 0, 0, 0);
          acc[3][j] = __builtin_amdgcn_mfma_f32_16x16x32_f16(a3, bf, acc[3][j], 0, 0, 0);
        }
      }
    }
#pragma unroll
    for (int i = 0; i < 4; ++i) {
      const int co = cg * 64 + i * 16 + kgrp * 4;
      floatx4 s = *(const floatx4*)(sc1v + co);
      floatx4 sh = *(const floatx4*)(sh1v + co);
#pragma unroll
      for (int j = 0; j < 2; ++j) {
        const int v = (lgrp * 2 + j) * 16 + lrow;
        const int l = l0 + v;
        if (v >= HALO && v < HALO + TOUT && l < LSEQ) {
          half4 h;
#pragma unroll
          for (int r = 0; r < 4; ++r)
            h[r] = (_Float16)fmaxf(acc[i][j][r] * s[r] + sh[r], 0.f);
          *(half4*)(dst + (((size_t)b * LSEQ + l) << 8) + co) = h;
        }
      }
    }
  }
}

// x[16][1][8192] -> h0[b][l][co] (f16) = relu(conv1d_{1->256}(x) + b_in)
__global__ void conv_in_kernel(const float* __restrict__ x, const float* __restrict__ w_in,
                               const float* __restrict__ b_in, _Float16* __restrict__ hout) {
  size_t idx = (size_t)blockIdx.x * blockDim.x + threadIdx.x;
  int co = (int)(idx & 255);
  size_t pos = idx >> 8;
  int l = (int)(pos & (LSEQ - 1));
  int b = (int)(pos >> 13);
  float acc = b_in[co];
#pragma unroll
  for (int k = 0; k < 3; ++k) {
    int lg = l + k - 1;
    if (lg >= 0 && lg < LSEQ) acc += w_in[co * 3 + k] * x[(size_t)b * LSEQ + lg];
  }
  hout[idx] = (_Float16)fmaxf(acc, 0.f);
}

// final conv 256->4 + bias + relu + pixel-shuffle: out[b][l*4+co]
__global__ __launch_bounds__(256) void conv_u2_kernel(
    const _Float16* __restrict__ hin, const float* __restrict__ w2T4 /*[tap][ci][4]*/,
    const float* __restrict__ b_u2, float* __restrict__ out) {
  const size_t idx = (size_t)blockIdx.x * 256 + threadIdx.x;  // = b*8192 + l
  const int l = (int)(idx & (LSEQ - 1));
  const int b = (int)(idx >> 13);
  floatx4 acc = *(const floatx4*)b_u2;
  for (int tap = 0; tap < 3; ++tap) {
    const int lg = l + tap - 1;
    if (lg < 0 || lg >= LSEQ) continue;
    const half8* hp = (const half8*)(hin + (((size_t)b * LSEQ + lg) << 8));
    const floatx4* wp = (const floatx4*)(w2T4 + tap * 1024);
    for (int q = 0; q < 32; ++q) {
      half8 hv = hp[q];
#pragma unroll
      for (int r = 0; r < 8; ++r) {
        floatx4 wv = wp[q * 8 + r];
        float h = (float)hv[r];
        acc[0] += h * wv[0]; acc[1] += h * wv[1]; acc[2] += h * wv[2]; acc[3] += h * wv[3];
      }
    }
  }
  floatx4 y;
#pragma unroll
  for (int r = 0; r < 4; ++r) y[r] = fmaxf(acc[r], 0.f);
  *(floatx4*)(out + ((size_t)b << 15) + (size_t)l * 4) = y;
}

// weight transforms + BN folding
__global__ void prep_kernel(
    const float* __restrict__ w_r1, const float* __restrict__ w_r2,
    const float* __restrict__ w_u1, const float* __restrict__ w_u2,
    const float* __restrict__ b_r1, const float* __restrict__ g1,
    const float* __restrict__ be1, const float* __restrict__ m1, const float* __restrict__ v1,
    const float* __restrict__ b_r2, const float* __restrict__ g2,
    const float* __restrict__ be2, const float* __restrict__ m2, const float* __restrict__ v2,
    const float* __restrict__ b_u1,
    _Float16* __restrict__ wT1, _Float16* __restrict__ wT2, _Float16* __restrict__ wTu1,
    float* __restrict__ wu2T4,
    float* __restrict__ sc1, float* __restrict__ sh1,
    float* __restrict__ sc2p, float* __restrict__ rs2, float* __restrict__ tsh,
    float* __restrict__ scu1, float* __restrict__ shu1) {
  int idx = blockIdx.x * blockDim.x + threadIdx.x;
  if (idx < 3 * CCH * CCH) {  // wT[tap][co][ci] = w[co][ci][tap]
    int tap = idx / (CCH * CCH);
    int rem = idx - tap * CCH * CCH;
    int co = rem >> 8, ci = rem & 255;
    size_t src = ((size_t)co * CCH + ci) * 3 + tap;
    wT1[idx] = (_Float16)w_r1[src];
    wT2[idx] = (_Float16)w_r2[src];
    wTu1[idx] = (_Float16)w_u1[src];
  }
  if (idx < 3 * CCH * 4) {  // wu2T4[tap][ci][co]
    int co = idx & 3;
    int ci = (idx >> 2) & 255;
    int tap = idx >> 10;
    wu2T4[idx] = w_u2[((size_t)co * CCH + ci) * 3 + tap];
  }
  if (idx < CCH) {
    float s1 = g1[idx] * rsqrtf(v1[idx] + 1e-5f);
    sc1[idx] = s1;
    sh1[idx] = (b_r1[idx] - m1[idx]) * s1 + be1[idx];
    float s2 = g2[idx] * rsqrtf(v2[idx] + 1e-5f);
    float sh2 = (b_r2[idx] - m2[idx]) * s2 + be2[idx];
    float sp = 0.15f * s2;
    sc2p[idx] = sp;
    rs2[idx] = 1.0f / sp;
    tsh[idx] = 0.15f * sh2 / sp;
    scu1[idx] = 1.f;
    shu1[idx] = b_u1[idx];
  }
}

__global__ void diag_kernel(float* out, float v) { out[0] = v; }

extern "C" void kernel_launch(void* const* d_in, const int* in_sizes, int n_in,
                              void* d_out, int out_size, void* d_ws, size_t ws_size,
                              hipStream_t stream) {
  (void)in_sizes; (void)n_in; (void)out_size;
  const size_t HELEMS = (size_t)16 * LSEQ * CCH;      // 33,554,432
  const size_t HB = HELEMS * sizeof(_Float16);        // 67,108,864
  const size_t NEED = 2 * HB + 2u * 1024 * 1024;      // ~136 MiB
  if (ws_size < NEED) {
    diag_kernel<<<1, 1, 0, stream>>>((float*)d_out, 1000.0f + (float)(ws_size >> 20));
    return;
  }
  const float* x    = (const float*)d_in[0];
  const float* w_in = (const float*)d_in[3];
  const float* b_in = (const float*)d_in[4];
  const float* w_r1 = (const float*)d_in[5];
  const float* b_r1 = (const float*)d_in[6];
  const float* g1   = (const float*)d_in[7];
  const float* be1  = (const float*)d_in[8];
  const float* m1   = (const float*)d_in[9];
  const float* v1   = (const float*)d_in[10];
  const float* w_r2 = (const float*)d_in[11];
  const float* b_r2 = (const float*)d_in[12];
  const float* g2   = (const float*)d_in[13];
  const float* be2  = (const float*)d_in[14];
  const float* m2   = (const float*)d_in[15];
  const float* v2   = (const float*)d_in[16];
  const float* w_u1 = (const float*)d_in[17];
  const float* b_u1 = (const float*)d_in[18];
  const float* w_u2 = (const float*)d_in[19];
  const float* b_u2 = (const float*)d_in[20];

  char* ws = (char*)d_ws;
  _Float16* buf0 = (_Float16*)ws;
  _Float16* buf1 = (_Float16*)(ws + HB);
  _Float16* wT1  = (_Float16*)(ws + 2 * HB);
  _Float16* wT2  = wT1 + 3 * CCH * CCH;
  _Float16* wTu1 = wT2 + 3 * CCH * CCH;
  float* sc1  = (float*)(wTu1 + 3 * CCH * CCH);
  float* sh1  = sc1 + CCH;
  float* sc2p = sh1 + CCH;
  float* rs2  = sc2p + CCH;
  float* tsh  = rs2 + CCH;
  float* scu1 = tsh + CCH;
  float* shu1 = scu1 + CCH;
  float* wu2T4 = shu1 + CCH;

  prep_kernel<<<768, 256, 0, stream>>>(w_r1, w_r2, w_u1, w_u2, b_r1, g1, be1, m1, v1,
                                       b_r2, g2, be2, m2, v2, b_u1,
                                       wT1, wT2, wTu1, wu2T4, sc1, sh1, sc2p, rs2, tsh,
                                       scu1, shu1);
  conv_in_kernel<<<131072, 256, 0, stream>>>(x, w_in, b_in, buf0);
  const int grid = 16 * NTILES;  // 1184
  for (int k = 0; k < 8; ++k) {  // 8 launches x 4 resblocks = 32
    const _Float16* s = (k & 1) ? buf1 : buf0;
    _Float16* d = (k & 1) ? buf0 : buf1;
    fused4<0><<<grid, 1024, 0, stream>>>(s, d, wT1, wT2, sc1, sh1, sc2p, rs2, tsh);
  }
  // after 8 launches state is in buf0
  fused4<1><<<grid, 1024, 0, stream>>>(buf0, buf1, wTu1, (const _Float16*)nullptr,
                                       scu1, shu1, (const float*)nullptr,
                                       (const float*)nullptr, (const float*)nullptr);
  conv_u2_kernel<<<512, 256, 0, stream>>>(buf1, wu2T4, b_u2, (float*)d_out);
}

// Round 8
// 42022.961 us; speedup vs baseline: 1.0476x; 1.0476x over previous
//
#include <hip/hip_runtime.h>

typedef _Float16 half8 __attribute__((ext_vector_type(8)));
typedef _Float16 half4 __attribute__((ext_vector_type(4)));
typedef float floatx4 __attribute__((ext_vector_type(4)));
typedef unsigned int uintx4 __attribute__((ext_vector_type(4)));

#define CCH 256
#define LSEQ 8192
#define TOUT 112                 // output rows per block
#define SROWS 128                // staged rows = TOUT + 4*RB
#define HALO 8                   // halo each side
#define RB 4                     // resblocks fused per launch
#define NTILES 74                // ceil(8192/112)
#define ROWB 512
#define R1OFF (SROWS * ROWB)     // 65536
#define LDSB (2 * SROWS * ROWB)  // 131072

__device__ __forceinline__ int swz(int row, int byte) {
  return row * ROWB + (byte ^ ((row & 7) << 4));
}
__device__ __forceinline__ floatx4 zero4() {
  floatx4 v; v[0] = 0.f; v[1] = 0.f; v[2] = 0.f; v[3] = 0.f; return v;
}
__device__ __forceinline__ int clampr(int r) {
  return r < 0 ? 0 : (r > SROWS - 1 ? SROWS - 1 : r);
}

// MODE 0: 4 fused resblocks. REGISTER-MINIMAL design (R8): h state lives ONLY in
//   LDS (f16). No cross-phase register arrays: conv1's acc dies at epi1; conv2's
//   accumulator is C-initialized from LDS h via the pre-scale trick
//   (c2 = h*rs2 + tsh; y = c2*sc2p) and dies at epi2. Peak live state =
//   32 accumulator f32 (AGPR-eligible) + 16 weight VGPRs + addressing < 64 arch
//   VGPRs, so the allocator's stubborn 64-cap (R4-R7: 13 GB/dispatch spill
//   traffic, unchangeable via launch_bounds/waves_per_eu) can no longer spill.
// MODE 1: single conv + affine + relu (up_block1).
template <int MODE>
__global__ __attribute__((amdgpu_flat_work_group_size(1024, 1024), amdgpu_waves_per_eu(4, 4)))
void fused4(
    const _Float16* __restrict__ src, _Float16* __restrict__ dst,
    const _Float16* __restrict__ wA, const _Float16* __restrict__ wB,
    const float* __restrict__ sc1v, const float* __restrict__ sh1v,
    const float* __restrict__ sc2pv, const float* __restrict__ rs2v,
    const float* __restrict__ tshv) {
  __shared__ __align__(16) char smem[LDSB];
  const int t = threadIdx.x;
  const int bx = blockIdx.x;
  const int b = bx / NTILES;
  const int tile = bx - b * NTILES;
  const int l0 = tile * TOUT - HALO;  // l of buffer row 0

  // ---- stage SROWS x 512B (f16) into swizzled LDS h-buffer (A)
  for (int c = t; c < SROWS * 32; c += 1024) {
    const int row = c >> 5, col = c & 31;
    const int l = l0 + row;
    uintx4 v = {0u, 0u, 0u, 0u};
    if (l >= 0 && l < LSEQ)
      v = *(const uintx4*)(src + (((size_t)b * LSEQ + l) << 8) + col * 8);
    *(uintx4*)(smem + swz(row, col * 16)) = v;
  }
  __syncthreads();

  const int w = t >> 6, ln = t & 63;
  const int cg = w >> 2, lgrp = w & 3;   // co-group 0..3, l-group 0..3
  const int lrow = ln & 15, kgrp = ln >> 4;

  if constexpr (MODE == 0) {
    for (int rb = 0; rb < RB; ++rb) {
      // ---- conv1: A -> acc (halo garbage creeps 2 rows/side per rb, within HALO)
      floatx4 acc[4][2];
#pragma unroll
      for (int i = 0; i < 4; ++i)
#pragma unroll
        for (int j = 0; j < 2; ++j) acc[i][j] = zero4();
      for (int tap = 0; tap < 3; ++tap) {
        for (int kc = 0; kc < 8; ++kc) {
          const _Float16* wp = wA + ((size_t)(tap * CCH + cg * 64 + lrow) * CCH) + kc * 32 + kgrp * 8;
          half8 a0 = *(const half8*)(wp);
          half8 a1 = *(const half8*)(wp + 16 * CCH);
          half8 a2 = *(const half8*)(wp + 32 * CCH);
          half8 a3 = *(const half8*)(wp + 48 * CCH);
          const int byt = kc * 64 + kgrp * 16;
#pragma unroll
          for (int j = 0; j < 2; ++j) {
            const int brow = clampr((lgrp * 2 + j) * 16 + lrow + tap - 1);
            half8 bf = *(const half8*)(smem + swz(brow, byt));
            acc[0][j] = __builtin_amdgcn_mfma_f32_16x16x32_f16(a0, bf, acc[0][j], 0, 0, 0);
            acc[1][j] = __builtin_amdgcn_mfma_f32_16x16x32_f16(a1, bf, acc[1][j], 0, 0, 0);
            acc[2][j] = __builtin_amdgcn_mfma_f32_16x16x32_f16(a2, bf, acc[2][j], 0, 0, 0);
            acc[3][j] = __builtin_amdgcn_mfma_f32_16x16x32_f16(a3, bf, acc[3][j], 0, 0, 0);
          }
        }
      }
      // epilogue 1: bn1+relu -> r1 (f16) into B buf, zero outside sequence
#pragma unroll
      for (int i = 0; i < 4; ++i) {
        const int co = cg * 64 + i * 16 + kgrp * 4;
        floatx4 s = *(const floatx4*)(sc1v + co);
        floatx4 sh = *(const floatx4*)(sh1v + co);
#pragma unroll
        for (int j = 0; j < 2; ++j) {
          const int v = (lgrp * 2 + j) * 16 + lrow;
          const int l = l0 + v;
          const bool valid = (l >= 0) && (l < LSEQ);
          unsigned long long pk = 0;
#pragma unroll
          for (int r = 0; r < 4; ++r) {
            float y = acc[i][j][r] * s[r] + sh[r];
            y = valid ? fmaxf(y, 0.f) : 0.f;
            unsigned short u = __builtin_bit_cast(unsigned short, (_Float16)y);
            pk |= (unsigned long long)u << (16 * r);
          }
          *(unsigned long long*)(smem + R1OFF + swz(v, co * 2)) = pk;
        }
      }
      __syncthreads();  // B complete; A reads (conv1) all done
      // ---- conv2 over r1(B), C-init from LDS h(A): c2 = h*rs2 + tsh
      floatx4 c2[4][2];
#pragma unroll
      for (int i = 0; i < 4; ++i) {
        const int co = cg * 64 + i * 16 + kgrp * 4;
        floatx4 rs = *(const floatx4*)(rs2v + co);
        floatx4 ts = *(const floatx4*)(tshv + co);
#pragma unroll
        for (int j = 0; j < 2; ++j) {
          const int v = (lgrp * 2 + j) * 16 + lrow;
          half4 h = *(const half4*)(smem + swz(v, co * 2));
#pragma unroll
          for (int r = 0; r < 4; ++r)
            c2[i][j][r] = (float)h[r] * rs[r] + ts[r];
        }
      }
      for (int tap = 0; tap < 3; ++tap) {
        for (int kc = 0; kc < 8; ++kc) {
          const _Float16* wp = wB + ((size_t)(tap * CCH + cg * 64 + lrow) * CCH) + kc * 32 + kgrp * 8;
          half8 a0 = *(const half8*)(wp);
          half8 a1 = *(const half8*)(wp + 16 * CCH);
          half8 a2 = *(const half8*)(wp + 32 * CCH);
          half8 a3 = *(const half8*)(wp + 48 * CCH);
          const int byt = kc * 64 + kgrp * 16;
#pragma unroll
          for (int j = 0; j < 2; ++j) {
            const int brow = clampr((lgrp * 2 + j) * 16 + lrow + tap - 1);
            half8 bf = *(const half8*)(smem + R1OFF + swz(brow, byt));
            c2[0][j] = __builtin_amdgcn_mfma_f32_16x16x32_f16(a0, bf, c2[0][j], 0, 0, 0);
            c2[1][j] = __builtin_amdgcn_mfma_f32_16x16x32_f16(a1, bf, c2[1][j], 0, 0, 0);
            c2[2][j] = __builtin_amdgcn_mfma_f32_16x16x32_f16(a2, bf, c2[2][j], 0, 0, 0);
            c2[3][j] = __builtin_amdgcn_mfma_f32_16x16x32_f16(a3, bf, c2[3][j], 0, 0, 0);
          }
        }
      }
      // epilogue 2: y = c2*sc2p (pin OOS to 0) -> A buf (f16)
#pragma unroll
      for (int i = 0; i < 4; ++i) {
        const int co = cg * 64 + i * 16 + kgrp * 4;
        floatx4 sp = *(const floatx4*)(sc2pv + co);
#pragma unroll
        for (int j = 0; j < 2; ++j) {
          const int v = (lgrp * 2 + j) * 16 + lrow;
          const int l = l0 + v;
          const bool valid = (l >= 0) && (l < LSEQ);
          unsigned long long pk = 0;
#pragma unroll
          for (int r = 0; r < 4; ++r) {
            float y = valid ? (c2[i][j][r] * sp[r]) : 0.f;
            unsigned short u = __builtin_bit_cast(unsigned short, (_Float16)y);
            pk |= (unsigned long long)u << (16 * r);
          }
          *(unsigned long long*)(smem + swz(v, co * 2)) = pk;
        }
      }
      __syncthreads();
    }
    // ---- write own output rows [HALO, HALO+TOUT) straight from LDS A (f16)
#pragma unroll
    for (int i = 0; i < 4; ++i) {
      const int co = cg * 64 + i * 16 + kgrp * 4;
#pragma unroll
      for (int j = 0; j < 2; ++j) {
        const int v = (lgrp * 2 + j) * 16 + lrow;
        const int l = l0 + v;
        if (v >= HALO && v < HALO + TOUT && l < LSEQ) {
          half4 h = *(const half4*)(smem + swz(v, co * 2));
          *(half4*)(dst + (((size_t)b * LSEQ + l) << 8) + co) = h;
        }
      }
    }
  } else {
    // MODE 1: out = relu(conv(h)*sc + sh), own rows only
    floatx4 acc[4][2];
#pragma unroll
    for (int i = 0; i < 4; ++i)
#pragma unroll
      for (int j = 0; j < 2; ++j) acc[i][j] = zero4();
    for (int tap = 0; tap < 3; ++tap) {
      for (int kc = 0; kc < 8; ++kc) {
        const _Float16* wp = wA + ((size_t)(tap * CCH + cg * 64 + lrow) * CCH) + kc * 32 + kgrp * 8;
        half8 a0 = *(const half8*)(wp);
        half8 a1 = *(const half8*)(wp + 16 * CCH);
        half8 a2 = *(const half8*)(wp + 32 * CCH);
        half8 a3 = *(const half8*)(wp + 48 * CCH);
        const int byt = kc * 64 + kgrp * 16;
#pragma unroll
        for (int j = 0; j < 2; ++j) {
          const int brow = clampr((lgrp * 2 + j) * 16 + lrow + tap - 1);
          half8 bf = *(const half8*)(smem + swz(brow, byt));
          acc[0][j] = __builtin_amdgcn_mfma_f32_16x16x32_f16(a0, bf, acc[0][j], 0, 0, 0);
          acc[1][j] = __builtin_amdgcn_mfma_f32_16x16x32_f16(a1, bf, acc[1][j], 0, 0, 0);
          acc[2][j] = __builtin_amdgcn_mfma_f32_16x16x32_f16(a2, bf, acc[2][j], 0, 0, 0);
          acc[3][j] = __builtin_amdgcn_mfma_f32_16x16x32_f16(a3, bf, acc[3][j], 0, 0, 0);
        }
      }
    }
#pragma unroll
    for (int i = 0; i < 4; ++i) {
      const int co = cg * 64 + i * 16 + kgrp * 4;
      floatx4 s = *(const floatx4*)(sc1v + co);
      floatx4 sh = *(const floatx4*)(sh1v + co);
#pragma unroll
      for (int j = 0; j < 2; ++j) {
        const int v = (lgrp * 2 + j) * 16 + lrow;
        const int l = l0 + v;
        if (v >= HALO && v < HALO + TOUT && l < LSEQ) {
          half4 h;
#pragma unroll
          for (int r = 0; r < 4; ++r)
            h[r] = (_Float16)fmaxf(acc[i][j][r] * s[r] + sh[r], 0.f);
          *(half4*)(dst + (((size_t)b * LSEQ + l) << 8) + co) = h;
        }
      }
    }
  }
}

// x[16][1][8192] -> h0[b][l][co] (f16) = relu(conv1d_{1->256}(x) + b_in)
__global__ void conv_in_kernel(const float* __restrict__ x, const float* __restrict__ w_in,
                               const float* __restrict__ b_in, _Float16* __restrict__ hout) {
  size_t idx = (size_t)blockIdx.x * blockDim.x + threadIdx.x;
  int co = (int)(idx & 255);
  size_t pos = idx >> 8;
  int l = (int)(pos & (LSEQ - 1));
  int b = (int)(pos >> 13);
  float acc = b_in[co];
#pragma unroll
  for (int k = 0; k < 3; ++k) {
    int lg = l + k - 1;
    if (lg >= 0 && lg < LSEQ) acc += w_in[co * 3 + k] * x[(size_t)b * LSEQ + lg];
  }
  hout[idx] = (_Float16)fmaxf(acc, 0.f);
}

// final conv 256->4 + bias + relu + pixel-shuffle: out[b][l*4+co]
__global__ __launch_bounds__(256) void conv_u2_kernel(
    const _Float16* __restrict__ hin, const float* __restrict__ w2T4 /*[tap][ci][4]*/,
    const float* __restrict__ b_u2, float* __restrict__ out) {
  const size_t idx = (size_t)blockIdx.x * 256 + threadIdx.x;  // = b*8192 + l
  const int l = (int)(idx & (LSEQ - 1));
  const int b = (int)(idx >> 13);
  floatx4 acc = *(const floatx4*)b_u2;
  for (int tap = 0; tap < 3; ++tap) {
    const int lg = l + tap - 1;
    if (lg < 0 || lg >= LSEQ) continue;
    const half8* hp = (const half8*)(hin + (((size_t)b * LSEQ + lg) << 8));
    const floatx4* wp = (const floatx4*)(w2T4 + tap * 1024);
    for (int q = 0; q < 32; ++q) {
      half8 hv = hp[q];
#pragma unroll
      for (int r = 0; r < 8; ++r) {
        floatx4 wv = wp[q * 8 + r];
        float h = (float)hv[r];
        acc[0] += h * wv[0]; acc[1] += h * wv[1]; acc[2] += h * wv[2]; acc[3] += h * wv[3];
      }
    }
  }
  floatx4 y;
#pragma unroll
  for (int r = 0; r < 4; ++r) y[r] = fmaxf(acc[r], 0.f);
  *(floatx4*)(out + ((size_t)b << 15) + (size_t)l * 4) = y;
}

// weight transforms + BN folding
__global__ void prep_kernel(
    const float* __restrict__ w_r1, const float* __restrict__ w_r2,
    const float* __restrict__ w_u1, const float* __restrict__ w_u2,
    const float* __restrict__ b_r1, const float* __restrict__ g1,
    const float* __restrict__ be1, const float* __restrict__ m1, const float* __restrict__ v1,
    const float* __restrict__ b_r2, const float* __restrict__ g2,
    const float* __restrict__ be2, const float* __restrict__ m2, const float* __restrict__ v2,
    const float* __restrict__ b_u1,
    _Float16* __restrict__ wT1, _Float16* __restrict__ wT2, _Float16* __restrict__ wTu1,
    float* __restrict__ wu2T4,
    float* __restrict__ sc1, float* __restrict__ sh1,
    float* __restrict__ sc2p, float* __restrict__ rs2, float* __restrict__ tsh,
    float* __restrict__ scu1, float* __restrict__ shu1) {
  int idx = blockIdx.x * blockDim.x + threadIdx.x;
  if (idx < 3 * CCH * CCH) {  // wT[tap][co][ci] = w[co][ci][tap]
    int tap = idx / (CCH * CCH);
    int rem = idx - tap * CCH * CCH;
    int co = rem >> 8, ci = rem & 255;
    size_t src = ((size_t)co * CCH + ci) * 3 + tap;
    wT1[idx] = (_Float16)w_r1[src];
    wT2[idx] = (_Float16)w_r2[src];
    wTu1[idx] = (_Float16)w_u1[src];
  }
  if (idx < 3 * CCH * 4) {  // wu2T4[tap][ci][co]
    int co = idx & 3;
    int ci = (idx >> 2) & 255;
    int tap = idx >> 10;
    wu2T4[idx] = w_u2[((size_t)co * CCH + ci) * 3 + tap];
  }
  if (idx < CCH) {
    float s1 = g1[idx] * rsqrtf(v1[idx] + 1e-5f);
    sc1[idx] = s1;
    sh1[idx] = (b_r1[idx] - m1[idx]) * s1 + be1[idx];
    float s2 = g2[idx] * rsqrtf(v2[idx] + 1e-5f);
    float sh2 = (b_r2[idx] - m2[idx]) * s2 + be2[idx];
    float sp = 0.15f * s2;
    sc2p[idx] = sp;
    rs2[idx] = 1.0f / sp;
    tsh[idx] = 0.15f * sh2 / sp;
    scu1[idx] = 1.f;
    shu1[idx] = b_u1[idx];
  }
}

__global__ void diag_kernel(float* out, float v) { out[0] = v; }

extern "C" void kernel_launch(void* const* d_in, const int* in_sizes, int n_in,
                              void* d_out, int out_size, void* d_ws, size_t ws_size,
                              hipStream_t stream) {
  (void)in_sizes; (void)n_in; (void)out_size;
  const size_t HELEMS = (size_t)16 * LSEQ * CCH;      // 33,554,432
  const size_t HB = HELEMS * sizeof(_Float16);        // 67,108,864
  const size_t NEED = 2 * HB + 2u * 1024 * 1024;      // ~136 MiB
  if (ws_size < NEED) {
    diag_kernel<<<1, 1, 0, stream>>>((float*)d_out, 1000.0f + (float)(ws_size >> 20));
    return;
  }
  const float* x    = (const float*)d_in[0];
  const float* w_in = (const float*)d_in[3];
  const float* b_in = (const float*)d_in[4];
  const float* w_r1 = (const float*)d_in[5];
  const float* b_r1 = (const float*)d_in[6];
  const float* g1   = (const float*)d_in[7];
  const float* be1  = (const float*)d_in[8];
  const float* m1   = (const float*)d_in[9];
  const float* v1   = (const float*)d_in[10];
  const float* w_r2 = (const float*)d_in[11];
  const float* b_r2 = (const float*)d_in[12];
  const float* g2   = (const float*)d_in[13];
  const float* be2  = (const float*)d_in[14];
  const float* m2   = (const float*)d_in[15];
  const float* v2   = (const float*)d_in[16];
  const float* w_u1 = (const float*)d_in[17];
  const float* b_u1 = (const float*)d_in[18];
  const float* w_u2 = (const float*)d_in[19];
  const float* b_u2 = (const float*)d_in[20];

  char* ws = (char*)d_ws;
  _Float16* buf0 = (_Float16*)ws;
  _Float16* buf1 = (_Float16*)(ws + HB);
  _Float16* wT1  = (_Float16*)(ws + 2 * HB);
  _Float16* wT2  = wT1 + 3 * CCH * CCH;
  _Float16* wTu1 = wT2 + 3 * CCH * CCH;
  float* sc1  = (float*)(wTu1 + 3 * CCH * CCH);
  float* sh1  = sc1 + CCH;
  float* sc2p = sh1 + CCH;
  float* rs2  = sc2p + CCH;
  float* tsh  = rs2 + CCH;
  float* scu1 = tsh + CCH;
  float* shu1 = scu1 + CCH;
  float* wu2T4 = shu1 + CCH;

  prep_kernel<<<768, 256, 0, stream>>>(w_r1, w_r2, w_u1, w_u2, b_r1, g1, be1, m1, v1,
                                       b_r2, g2, be2, m2, v2, b_u1,
                                       wT1, wT2, wTu1, wu2T4, sc1, sh1, sc2p, rs2, tsh,
                                       scu1, shu1);
  conv_in_kernel<<<131072, 256, 0, stream>>>(x, w_in, b_in, buf0);
  const int grid = 16 * NTILES;  // 1184
  for (int k = 0; k < 8; ++k) {  // 8 launches x 4 resblocks = 32
    const _Float16* s = (k & 1) ? buf1 : buf0;
    _Float16* d = (k & 1) ? buf0 : buf1;
    fused4<0><<<grid, 1024, 0, stream>>>(s, d, wT1, wT2, sc1, sh1, sc2p, rs2, tsh);
  }
  // after 8 launches state is in buf0
  fused4<1><<<grid, 1024, 0, stream>>>(buf0, buf1, wTu1, (const _Float16*)nullptr,
                                       scu1, shu1, (const float*)nullptr,
                                       (const float*)nullptr, (const float*)nullptr);
  conv_u2_kernel<<<512, 256, 0, stream>>>(buf1, wu2T4, b_u2, (float*)d_out);
}

// Round 9
// 11714.047 us; speedup vs baseline: 3.7583x; 3.5874x over previous
//
#include <hip/hip_runtime.h>

typedef _Float16 half8 __attribute__((ext_vector_type(8)));
typedef _Float16 half4 __attribute__((ext_vector_type(4)));
typedef float floatx4 __attribute__((ext_vector_type(4)));
typedef unsigned int uintx4 __attribute__((ext_vector_type(4)));

#define CCH 256
#define LSEQ 8192
#define LTILE 64                  // output rows per block
#define AROWS 68                  // staged h rows: l0-2 .. l0+65
#define BROWS 66                  // r1 rows: l0-1 .. l0+64
#define NT2 128                   // tiles per batch = 8192/64
#define ROWB 512
#define BOFF (AROWS * ROWB)       // 34816
#define LDSB (BOFF + BROWS * ROWB)  // 68608 -> 2 blocks/CU

__device__ __forceinline__ int swz(int row, int byte) {
  return row * ROWB + (byte ^ ((row & 7) << 4));
}
__device__ __forceinline__ floatx4 zero4() {
  floatx4 v; v[0] = 0.f; v[1] = 0.f; v[2] = 0.f; v[3] = 0.f; return v;
}

// Back to the R2-proven per-resblock structure (best measured: 278 us/dispatch,
// VGPR=88, no spill/traffic pathology), improved by:
//  - f16 global state, ping-pong src->dst (no stash, no in-place hazard);
//    numerically validated in R8 (absmax 9.77e-4 with per-rb f16 rounding)
//  - LTILE=64 -> LDS 68.6 KB -> 2 blocks/CU for cross-block latency overlap
// MODE 0: dst = src + 0.15*bn2(conv2(relu(bn1(conv1(src)))))
// MODE 1: dst = relu(conv(src)*sc + sh)   (up_block1)
template <int MODE>
__global__ __launch_bounds__(512, 1) void res1(
    const _Float16* __restrict__ src, _Float16* __restrict__ dst,
    const _Float16* __restrict__ wA, const _Float16* __restrict__ wB,
    const float* __restrict__ sc1v, const float* __restrict__ sh1v,
    const float* __restrict__ sc2v, const float* __restrict__ sh2v) {
  __shared__ __align__(16) char smem[LDSB];
  const int t = threadIdx.x;
  const int bx = blockIdx.x;
  const int b = bx >> 7;
  const int tile = bx & (NT2 - 1);
  const int l0 = tile * LTILE;

  // ---- stage A: 68 rows (row <-> l = l0-2+row), f16, swizzled, zero-padded
  for (int c = t; c < AROWS * 32; c += 512) {
    const int row = c >> 5, col = c & 31;
    const int l = l0 + row - 2;
    uintx4 v = {0u, 0u, 0u, 0u};
    if (l >= 0 && l < LSEQ)
      v = *(const uintx4*)(src + (((size_t)b * LSEQ + l) << 8) + col * 8);
    *(uintx4*)(smem + swz(row, col * 16)) = v;
  }
  __syncthreads();

  const int w = t >> 6, ln = t & 63;
  const int cg = w >> 1, lgrp = w & 1;  // co-group 0..3, l-half 0..1
  const int lrow = ln & 15, kgrp = ln >> 4;

  if constexpr (MODE == 0) {
    // ---- conv1 -> r1 rows r (l = l0-1+r): lgrp0 covers jt 0..2 (r 0..47),
    //      lgrp1 jt 3..4 (r 48..79; valid to 65)
    const int jtb = lgrp ? 3 : 0;
    const int njt = lgrp ? 2 : 3;
    floatx4 acc[4][3];
#pragma unroll
    for (int i = 0; i < 4; ++i)
#pragma unroll
      for (int j = 0; j < 3; ++j) acc[i][j] = zero4();
    for (int tap = 0; tap < 3; ++tap) {
      for (int kc = 0; kc < 8; ++kc) {
        const _Float16* wp = wA + ((size_t)(tap * CCH + cg * 64 + lrow) * CCH) + kc * 32 + kgrp * 8;
        half8 a0 = *(const half8*)(wp);
        half8 a1 = *(const half8*)(wp + 16 * CCH);
        half8 a2 = *(const half8*)(wp + 32 * CCH);
        half8 a3 = *(const half8*)(wp + 48 * CCH);
        const int byt = kc * 64 + kgrp * 16;
#pragma unroll
        for (int jj = 0; jj < 3; ++jj) {
          if (jj < njt) {
            int arow = (jtb + jj) * 16 + lrow + tap;  // A row = r + tap
            if (arow > AROWS - 1) arow = AROWS - 1;   // masked outputs only
            half8 bf = *(const half8*)(smem + swz(arow, byt));
            acc[0][jj] = __builtin_amdgcn_mfma_f32_16x16x32_f16(a0, bf, acc[0][jj], 0, 0, 0);
            acc[1][jj] = __builtin_amdgcn_mfma_f32_16x16x32_f16(a1, bf, acc[1][jj], 0, 0, 0);
            acc[2][jj] = __builtin_amdgcn_mfma_f32_16x16x32_f16(a2, bf, acc[2][jj], 0, 0, 0);
            acc[3][jj] = __builtin_amdgcn_mfma_f32_16x16x32_f16(a3, bf, acc[3][jj], 0, 0, 0);
          }
        }
      }
    }
    // epilogue 1: bn1+relu -> B (f16); zero outside sequence; skip r >= 66
#pragma unroll
    for (int i = 0; i < 4; ++i) {
      const int co = cg * 64 + i * 16 + kgrp * 4;
      floatx4 s = *(const floatx4*)(sc1v + co);
      floatx4 sh = *(const floatx4*)(sh1v + co);
#pragma unroll
      for (int jj = 0; jj < 3; ++jj) {
        if (jj < njt) {
          const int r = (jtb + jj) * 16 + lrow;
          if (r < BROWS) {
            const int l = l0 - 1 + r;
            const bool valid = (l >= 0) && (l < LSEQ);
            unsigned long long pk = 0;
#pragma unroll
            for (int q = 0; q < 4; ++q) {
              float y = acc[i][jj][q] * s[q] + sh[q];
              y = valid ? fmaxf(y, 0.f) : 0.f;
              unsigned short u = __builtin_bit_cast(unsigned short, (_Float16)y);
              pk |= (unsigned long long)u << (16 * q);
            }
            *(unsigned long long*)(smem + BOFF + swz(r, co * 2)) = pk;
          }
        }
      }
    }
    __syncthreads();
    // ---- conv2: out row v (l = l0+v), reads B rows v..v+2; lgrp covers 2 tiles
    floatx4 acc2[4][2];
#pragma unroll
    for (int i = 0; i < 4; ++i)
#pragma unroll
      for (int j = 0; j < 2; ++j) acc2[i][j] = zero4();
    for (int tap = 0; tap < 3; ++tap) {
      for (int kc = 0; kc < 8; ++kc) {
        const _Float16* wp = wB + ((size_t)(tap * CCH + cg * 64 + lrow) * CCH) + kc * 32 + kgrp * 8;
        half8 a0 = *(const half8*)(wp);
        half8 a1 = *(const half8*)(wp + 16 * CCH);
        half8 a2 = *(const half8*)(wp + 32 * CCH);
        half8 a3 = *(const half8*)(wp + 48 * CCH);
        const int byt = kc * 64 + kgrp * 16;
#pragma unroll
        for (int j = 0; j < 2; ++j) {
          const int brow = (lgrp * 2 + j) * 16 + lrow + tap;  // 0..65
          half8 bf = *(const half8*)(smem + BOFF + swz(brow, byt));
          acc2[0][j] = __builtin_amdgcn_mfma_f32_16x16x32_f16(a0, bf, acc2[0][j], 0, 0, 0);
          acc2[1][j] = __builtin_amdgcn_mfma_f32_16x16x32_f16(a1, bf, acc2[1][j], 0, 0, 0);
          acc2[2][j] = __builtin_amdgcn_mfma_f32_16x16x32_f16(a2, bf, acc2[2][j], 0, 0, 0);
          acc2[3][j] = __builtin_amdgcn_mfma_f32_16x16x32_f16(a3, bf, acc2[3][j], 0, 0, 0);
        }
      }
    }
    // epilogue 2: y = h + 0.15*bn2 (h from A rows v+2), write dst (f16)
#pragma unroll
    for (int i = 0; i < 4; ++i) {
      const int co = cg * 64 + i * 16 + kgrp * 4;
      floatx4 s = *(const floatx4*)(sc2v + co);
      floatx4 sh = *(const floatx4*)(sh2v + co);
#pragma unroll
      for (int j = 0; j < 2; ++j) {
        const int v = (lgrp * 2 + j) * 16 + lrow;
        const int l = l0 + v;
        half4 h = *(const half4*)(smem + swz(v + 2, co * 2));
        half4 o;
#pragma unroll
        for (int q = 0; q < 4; ++q)
          o[q] = (_Float16)((float)h[q] + 0.15f * (acc2[i][j][q] * s[q] + sh[q]));
        *(half4*)(dst + (((size_t)b * LSEQ + l) << 8) + co) = o;
      }
    }
  } else {
    // MODE 1: out = relu(conv(A)*sc + sh); out row v reads A rows v+1..v+3
    floatx4 acc[4][2];
#pragma unroll
    for (int i = 0; i < 4; ++i)
#pragma unroll
      for (int j = 0; j < 2; ++j) acc[i][j] = zero4();
    for (int tap = 0; tap < 3; ++tap) {
      for (int kc = 0; kc < 8; ++kc) {
        const _Float16* wp = wA + ((size_t)(tap * CCH + cg * 64 + lrow) * CCH) + kc * 32 + kgrp * 8;
        half8 a0 = *(const half8*)(wp);
        half8 a1 = *(const half8*)(wp + 16 * CCH);
        half8 a2 = *(const half8*)(wp + 32 * CCH);
        half8 a3 = *(const half8*)(wp + 48 * CCH);
        const int byt = kc * 64 + kgrp * 16;
#pragma unroll
        for (int j = 0; j < 2; ++j) {
          const int arow = (lgrp * 2 + j) * 16 + lrow + 1 + tap;  // 1..66
          half8 bf = *(const half8*)(smem + swz(arow, byt));
          acc[0][j] = __builtin_amdgcn_mfma_f32_16x16x32_f16(a0, bf, acc[0][j], 0, 0, 0);
          acc[1][j] = __builtin_amdgcn_mfma_f32_16x16x32_f16(a1, bf, acc[1][j], 0, 0, 0);
          acc[2][j] = __builtin_amdgcn_mfma_f32_16x16x32_f16(a2, bf, acc[2][j], 0, 0, 0);
          acc[3][j] = __builtin_amdgcn_mfma_f32_16x16x32_f16(a3, bf, acc[3][j], 0, 0, 0);
        }
      }
    }
#pragma unroll
    for (int i = 0; i < 4; ++i) {
      const int co = cg * 64 + i * 16 + kgrp * 4;
      floatx4 s = *(const floatx4*)(sc1v + co);
      floatx4 sh = *(const floatx4*)(sh1v + co);
#pragma unroll
      for (int j = 0; j < 2; ++j) {
        const int v = (lgrp * 2 + j) * 16 + lrow;
        const int l = l0 + v;
        half4 o;
#pragma unroll
        for (int q = 0; q < 4; ++q)
          o[q] = (_Float16)fmaxf(acc[i][j][q] * s[q] + sh[q], 0.f);
        *(half4*)(dst + (((size_t)b * LSEQ + l) << 8) + co) = o;
      }
    }
  }
}

// x[16][1][8192] -> h0[b][l][co] (f16) = relu(conv1d_{1->256}(x) + b_in)
__global__ void conv_in_kernel(const float* __restrict__ x, const float* __restrict__ w_in,
                               const float* __restrict__ b_in, _Float16* __restrict__ hout) {
  size_t idx = (size_t)blockIdx.x * blockDim.x + threadIdx.x;
  int co = (int)(idx & 255);
  size_t pos = idx >> 8;
  int l = (int)(pos & (LSEQ - 1));
  int b = (int)(pos >> 13);
  float acc = b_in[co];
#pragma unroll
  for (int k = 0; k < 3; ++k) {
    int lg = l + k - 1;
    if (lg >= 0 && lg < LSEQ) acc += w_in[co * 3 + k] * x[(size_t)b * LSEQ + lg];
  }
  hout[idx] = (_Float16)fmaxf(acc, 0.f);
}

// final conv 256->4 + bias + relu + pixel-shuffle: out[b][l*4+co]
__global__ __launch_bounds__(256) void conv_u2_kernel(
    const _Float16* __restrict__ hin, const float* __restrict__ w2T4 /*[tap][ci][4]*/,
    const float* __restrict__ b_u2, float* __restrict__ out) {
  const size_t idx = (size_t)blockIdx.x * 256 + threadIdx.x;  // = b*8192 + l
  const int l = (int)(idx & (LSEQ - 1));
  const int b = (int)(idx >> 13);
  floatx4 acc = *(const floatx4*)b_u2;
  for (int tap = 0; tap < 3; ++tap) {
    const int lg = l + tap - 1;
    if (lg < 0 || lg >= LSEQ) continue;
    const half8* hp = (const half8*)(hin + (((size_t)b * LSEQ + lg) << 8));
    const floatx4* wp = (const floatx4*)(w2T4 + tap * 1024);
    for (int q = 0; q < 32; ++q) {
      half8 hv = hp[q];
#pragma unroll
      for (int r = 0; r < 8; ++r) {
        floatx4 wv = wp[q * 8 + r];
        float h = (float)hv[r];
        acc[0] += h * wv[0]; acc[1] += h * wv[1]; acc[2] += h * wv[2]; acc[3] += h * wv[3];
      }
    }
  }
  floatx4 y;
#pragma unroll
  for (int r = 0; r < 4; ++r) y[r] = fmaxf(acc[r], 0.f);
  *(floatx4*)(out + ((size_t)b << 15) + (size_t)l * 4) = y;
}

// weight transforms + BN folding
__global__ void prep_kernel(
    const float* __restrict__ w_r1, const float* __restrict__ w_r2,
    const float* __restrict__ w_u1, const float* __restrict__ w_u2,
    const float* __restrict__ b_r1, const float* __restrict__ g1,
    const float* __restrict__ be1, const float* __restrict__ m1, const float* __restrict__ v1,
    const float* __restrict__ b_r2, const float* __restrict__ g2,
    const float* __restrict__ be2, const float* __restrict__ m2, const float* __restrict__ v2,
    const float* __restrict__ b_u1,
    _Float16* __restrict__ wT1, _Float16* __restrict__ wT2, _Float16* __restrict__ wTu1,
    float* __restrict__ wu2T4,
    float* __restrict__ sc1, float* __restrict__ sh1,
    float* __restrict__ sc2, float* __restrict__ sh2,
    float* __restrict__ scu1, float* __restrict__ shu1) {
  int idx = blockIdx.x * blockDim.x + threadIdx.x;
  if (idx < 3 * CCH * CCH) {  // wT[tap][co][ci] = w[co][ci][tap]
    int tap = idx / (CCH * CCH);
    int rem = idx - tap * CCH * CCH;
    int co = rem >> 8, ci = rem & 255;
    size_t src = ((size_t)co * CCH + ci) * 3 + tap;
    wT1[idx] = (_Float16)w_r1[src];
    wT2[idx] = (_Float16)w_r2[src];
    wTu1[idx] = (_Float16)w_u1[src];
  }
  if (idx < 3 * CCH * 4) {  // wu2T4[tap][ci][co]
    int co = idx & 3;
    int ci = (idx >> 2) & 255;
    int tap = idx >> 10;
    wu2T4[idx] = w_u2[((size_t)co * CCH + ci) * 3 + tap];
  }
  if (idx < CCH) {
    float s1 = g1[idx] * rsqrtf(v1[idx] + 1e-5f);
    sc1[idx] = s1;
    sh1[idx] = (b_r1[idx] - m1[idx]) * s1 + be1[idx];
    float s2 = g2[idx] * rsqrtf(v2[idx] + 1e-5f);
    sc2[idx] = s2;
    sh2[idx] = (b_r2[idx] - m2[idx]) * s2 + be2[idx];
    scu1[idx] = 1.f;
    shu1[idx] = b_u1[idx];
  }
}

__global__ void diag_kernel(float* out, float v) { out[0] = v; }

extern "C" void kernel_launch(void* const* d_in, const int* in_sizes, int n_in,
                              void* d_out, int out_size, void* d_ws, size_t ws_size,
                              hipStream_t stream) {
  (void)in_sizes; (void)n_in; (void)out_size;
  const size_t HELEMS = (size_t)16 * LSEQ * CCH;      // 33,554,432
  const size_t HB = HELEMS * sizeof(_Float16);        // 67,108,864
  const size_t NEED = 2 * HB + 2u * 1024 * 1024;      // ~136 MiB
  if (ws_size < NEED) {
    diag_kernel<<<1, 1, 0, stream>>>((float*)d_out, 1000.0f + (float)(ws_size >> 20));
    return;
  }
  const float* x    = (const float*)d_in[0];
  const float* w_in = (const float*)d_in[3];
  const float* b_in = (const float*)d_in[4];
  const float* w_r1 = (const float*)d_in[5];
  const float* b_r1 = (const float*)d_in[6];
  const float* g1   = (const float*)d_in[7];
  const float* be1  = (const float*)d_in[8];
  const float* m1   = (const float*)d_in[9];
  const float* v1   = (const float*)d_in[10];
  const float* w_r2 = (const float*)d_in[11];
  const float* b_r2 = (const float*)d_in[12];
  const float* g2   = (const float*)d_in[13];
  const float* be2  = (const float*)d_in[14];
  const float* m2   = (const float*)d_in[15];
  const float* v2   = (const float*)d_in[16];
  const float* w_u1 = (const float*)d_in[17];
  const float* b_u1 = (const float*)d_in[18];
  const float* w_u2 = (const float*)d_in[19];
  const float* b_u2 = (const float*)d_in[20];

  char* ws = (char*)d_ws;
  _Float16* buf0 = (_Float16*)ws;
  _Float16* buf1 = (_Float16*)(ws + HB);
  _Float16* wT1  = (_Float16*)(ws + 2 * HB);
  _Float16* wT2  = wT1 + 3 * CCH * CCH;
  _Float16* wTu1 = wT2 + 3 * CCH * CCH;
  float* sc1  = (float*)(wTu1 + 3 * CCH * CCH);
  float* sh1  = sc1 + CCH;
  float* sc2  = sh1 + CCH;
  float* sh2  = sc2 + CCH;
  float* scu1 = sh2 + CCH;
  float* shu1 = scu1 + CCH;
  float* wu2T4 = shu1 + CCH;

  prep_kernel<<<768, 256, 0, stream>>>(w_r1, w_r2, w_u1, w_u2, b_r1, g1, be1, m1, v1,
                                       b_r2, g2, be2, m2, v2, b_u1,
                                       wT1, wT2, wTu1, wu2T4, sc1, sh1, sc2, sh2, scu1, shu1);
  conv_in_kernel<<<131072, 256, 0, stream>>>(x, w_in, b_in, buf0);
  const int grid = 16 * NT2;  // 2048
  for (int k = 0; k < 32; ++k) {
    const _Float16* s = (k & 1) ? buf1 : buf0;
    _Float16* d = (k & 1) ? buf0 : buf1;
    res1<0><<<grid, 512, 0, stream>>>(s, d, wT1, wT2, sc1, sh1, sc2, sh2);
  }
  // state in buf0 after 32 resblocks
  res1<1><<<grid, 512, 0, stream>>>(buf0, buf1, wTu1, (const _Float16*)nullptr,
                                    scu1, shu1, (const float*)nullptr, (const float*)nullptr);
  conv_u2_kernel<<<512, 256, 0, stream>>>(buf1, wu2T4, b_u2, (float*)d_out);
}

// Round 10
// 5664.769 us; speedup vs baseline: 7.7717x; 2.0679x over previous
//
#include <hip/hip_runtime.h>

typedef _Float16 half8 __attribute__((ext_vector_type(8)));
typedef _Float16 half4 __attribute__((ext_vector_type(4)));
typedef float floatx4 __attribute__((ext_vector_type(4)));
typedef unsigned int uintx4 __attribute__((ext_vector_type(4)));

#define CCH 256
#define LSEQ 8192
#define LTILE 128                 // output rows per block
#define AROWS 132                 // staged h rows: l0-2 .. l0+129
#define NT 64                     // tiles per batch = 8192/128
#define ROWB 512
#define LDSB (AROWS * ROWB)       // 67584 -> 2 blocks/CU

__device__ __forceinline__ int swz(int row, int byte) {
  return row * ROWB + (byte ^ ((row & 7) << 4));
}
__device__ __forceinline__ floatx4 zero4() {
  floatx4 v; v[0] = 0.f; v[1] = 0.f; v[2] = 0.f; v[3] = 0.f; return v;
}

// R10: R2-proven structure (512 thr, LTILE=128, launch_bounds(512,1) -> VGPR>64)
// with the two fixes diagnosed in R9:
//  - DENSE weight layout [tap][kc][co][32ci]: each A-fragment wave-load is 1KB
//    contiguous (was a 16-cacheline strided gather -> 16x request amplification,
//    the real source of R4-R9's phantom traffic / latency)
//  - single shared LDS buffer (h then r1, R3-proven barrier) -> 67.6KB, 2 blk/CU;
//    residual h re-read from global src (f16 ping-pong, LLC-resident)
// MODE 0: dst = src + 0.15*bn2(conv2(relu(bn1(conv1(src)))))
// MODE 1: dst = relu(conv(src)*sc + sh)
template <int MODE>
__global__ __launch_bounds__(512, 1) void res2(
    const _Float16* __restrict__ src, _Float16* __restrict__ dst,
    const _Float16* __restrict__ wA, const _Float16* __restrict__ wB,
    const float* __restrict__ sc1v, const float* __restrict__ sh1v,
    const float* __restrict__ sc2v, const float* __restrict__ sh2v) {
  __shared__ __align__(16) char smem[LDSB];
  const int t = threadIdx.x;
  const int bx = blockIdx.x;
  const int b = bx >> 6;
  const int tile = bx & (NT - 1);
  const int l0 = tile * LTILE;

  // ---- stage A: 132 rows (row <-> l = l0-2+row), f16, swizzled, zero-padded
  for (int c = t; c < AROWS * 32; c += 512) {
    const int row = c >> 5, col = c & 31;
    const int l = l0 + row - 2;
    uintx4 v = {0u, 0u, 0u, 0u};
    if (l >= 0 && l < LSEQ)
      v = *(const uintx4*)(src + (((size_t)b * LSEQ + l) << 8) + col * 8);
    *(uintx4*)(smem + swz(row, col * 16)) = v;
  }
  __syncthreads();

  const int w = t >> 6, ln = t & 63;
  const int cg = w >> 1, lgrp = w & 1;  // co-group 0..3, l-half 0..1
  const int lrow = ln & 15, kgrp = ln >> 4;

  if constexpr (MODE == 0) {
    // ---- conv1 -> r1 rows r (l = l0-1+r), r 0..129 used.
    // lgrp0: j-tiles 0..4 (r 0..79); lgrp1: tiles 5..8 (r 80..143, masked >=130)
    const int jtb = lgrp * 5;
    const int njt = lgrp ? 4 : 5;
    floatx4 acc[4][5];
#pragma unroll
    for (int i = 0; i < 4; ++i)
#pragma unroll
      for (int j = 0; j < 5; ++j) acc[i][j] = zero4();
    for (int tap = 0; tap < 3; ++tap) {
      for (int kc = 0; kc < 8; ++kc) {
        // dense: wA[((tap*8+kc)*256 + co)*32 + kgrp*8], co = cg*64+i*16+lrow
        const _Float16* wp = wA + ((size_t)((tap * 8 + kc) * CCH + cg * 64 + lrow)) * 32 + kgrp * 8;
        half8 a0 = *(const half8*)(wp);
        half8 a1 = *(const half8*)(wp + 16 * 32);
        half8 a2 = *(const half8*)(wp + 32 * 32);
        half8 a3 = *(const half8*)(wp + 48 * 32);
        const int byt = kc * 64 + kgrp * 16;
#pragma unroll
        for (int jj = 0; jj < 5; ++jj) {
          if (jj < njt) {
            int arow = (jtb + jj) * 16 + lrow + tap;  // A row = r + tap
            if (arow > AROWS - 1) arow = AROWS - 1;   // masked outputs only
            half8 bf = *(const half8*)(smem + swz(arow, byt));
            acc[0][jj] = __builtin_amdgcn_mfma_f32_16x16x32_f16(a0, bf, acc[0][jj], 0, 0, 0);
            acc[1][jj] = __builtin_amdgcn_mfma_f32_16x16x32_f16(a1, bf, acc[1][jj], 0, 0, 0);
            acc[2][jj] = __builtin_amdgcn_mfma_f32_16x16x32_f16(a2, bf, acc[2][jj], 0, 0, 0);
            acc[3][jj] = __builtin_amdgcn_mfma_f32_16x16x32_f16(a3, bf, acc[3][jj], 0, 0, 0);
          }
        }
      }
    }
    __syncthreads();  // all conv1 A-reads done before r1 overwrites the buffer
    // epilogue 1: bn1+relu -> r1 into SAME buffer at row r; zero outside seq
#pragma unroll
    for (int i = 0; i < 4; ++i) {
      const int co = cg * 64 + i * 16 + kgrp * 4;
      floatx4 s = *(const floatx4*)(sc1v + co);
      floatx4 sh = *(const floatx4*)(sh1v + co);
#pragma unroll
      for (int jj = 0; jj < 5; ++jj) {
        if (jj < njt) {
          const int r = (jtb + jj) * 16 + lrow;
          if (r < 130) {
            const int l = l0 - 1 + r;
            const bool valid = (l >= 0) && (l < LSEQ);
            unsigned long long pk = 0;
#pragma unroll
            for (int q = 0; q < 4; ++q) {
              float y = acc[i][jj][q] * s[q] + sh[q];
              y = valid ? fmaxf(y, 0.f) : 0.f;
              unsigned short u = __builtin_bit_cast(unsigned short, (_Float16)y);
              pk |= (unsigned long long)u << (16 * q);
            }
            *(unsigned long long*)(smem + swz(r, co * 2)) = pk;
          }
        }
      }
    }
    __syncthreads();
    // ---- conv2: out row v (l = l0+v), reads r1 rows v..v+2; 4 j-tiles per lgrp
    floatx4 acc2[4][4];
#pragma unroll
    for (int i = 0; i < 4; ++i)
#pragma unroll
      for (int j = 0; j < 4; ++j) acc2[i][j] = zero4();
    for (int tap = 0; tap < 3; ++tap) {
      for (int kc = 0; kc < 8; ++kc) {
        const _Float16* wp = wB + ((size_t)((tap * 8 + kc) * CCH + cg * 64 + lrow)) * 32 + kgrp * 8;
        half8 a0 = *(const half8*)(wp);
        half8 a1 = *(const half8*)(wp + 16 * 32);
        half8 a2 = *(const half8*)(wp + 32 * 32);
        half8 a3 = *(const half8*)(wp + 48 * 32);
        const int byt = kc * 64 + kgrp * 16;
#pragma unroll
        for (int j = 0; j < 4; ++j) {
          const int brow = (lgrp * 4 + j) * 16 + lrow + tap;  // 0..129
          half8 bf = *(const half8*)(smem + swz(brow, byt));
          acc2[0][j] = __builtin_amdgcn_mfma_f32_16x16x32_f16(a0, bf, acc2[0][j], 0, 0, 0);
          acc2[1][j] = __builtin_amdgcn_mfma_f32_16x16x32_f16(a1, bf, acc2[1][j], 0, 0, 0);
          acc2[2][j] = __builtin_amdgcn_mfma_f32_16x16x32_f16(a2, bf, acc2[2][j], 0, 0, 0);
          acc2[3][j] = __builtin_amdgcn_mfma_f32_16x16x32_f16(a3, bf, acc2[3][j], 0, 0, 0);
        }
      }
    }
    // epilogue 2: y = h + 0.15*bn2; h re-read from global src (LLC-resident)
#pragma unroll
    for (int i = 0; i < 4; ++i) {
      const int co = cg * 64 + i * 16 + kgrp * 4;
      floatx4 s = *(const floatx4*)(sc2v + co);
      floatx4 sh = *(const floatx4*)(sh2v + co);
#pragma unroll
      for (int j = 0; j < 4; ++j) {
        const int v = (lgrp * 4 + j) * 16 + lrow;
        const int l = l0 + v;
        const size_t off = (((size_t)b * LSEQ + l) << 8) + co;
        half4 h = *(const half4*)(src + off);
        half4 o;
#pragma unroll
        for (int q = 0; q < 4; ++q)
          o[q] = (_Float16)((float)h[q] + 0.15f * (acc2[i][j][q] * s[q] + sh[q]));
        *(half4*)(dst + off) = o;
      }
    }
  } else {
    // MODE 1: out = relu(conv(A)*sc + sh); out row v reads A rows v+1..v+3
    floatx4 acc[4][4];
#pragma unroll
    for (int i = 0; i < 4; ++i)
#pragma unroll
      for (int j = 0; j < 4; ++j) acc[i][j] = zero4();
    for (int tap = 0; tap < 3; ++tap) {
      for (int kc = 0; kc < 8; ++kc) {
        const _Float16* wp = wA + ((size_t)((tap * 8 + kc) * CCH + cg * 64 + lrow)) * 32 + kgrp * 8;
        half8 a0 = *(const half8*)(wp);
        half8 a1 = *(const half8*)(wp + 16 * 32);
        half8 a2 = *(const half8*)(wp + 32 * 32);
        half8 a3 = *(const half8*)(wp + 48 * 32);
        const int byt = kc * 64 + kgrp * 16;
#pragma unroll
        for (int j = 0; j < 4; ++j) {
          const int arow = (lgrp * 4 + j) * 16 + lrow + 1 + tap;  // 1..130
          half8 bf = *(const half8*)(smem + swz(arow, byt));
          acc[0][j] = __builtin_amdgcn_mfma_f32_16x16x32_f16(a0, bf, acc[0][j], 0, 0, 0);
          acc[1][j] = __builtin_amdgcn_mfma_f32_16x16x32_f16(a1, bf, acc[1][j], 0, 0, 0);
          acc[2][j] = __builtin_amdgcn_mfma_f32_16x16x32_f16(a2, bf, acc[2][j], 0, 0, 0);
          acc[3][j] = __builtin_amdgcn_mfma_f32_16x16x32_f16(a3, bf, acc[3][j], 0, 0, 0);
        }
      }
    }
#pragma unroll
    for (int i = 0; i < 4; ++i) {
      const int co = cg * 64 + i * 16 + kgrp * 4;
      floatx4 s = *(const floatx4*)(sc1v + co);
      floatx4 sh = *(const floatx4*)(sh1v + co);
#pragma unroll
      for (int j = 0; j < 4; ++j) {
        const int v = (lgrp * 4 + j) * 16 + lrow;
        const int l = l0 + v;
        half4 o;
#pragma unroll
        for (int q = 0; q < 4; ++q)
          o[q] = (_Float16)fmaxf(acc[i][j][q] * s[q] + sh[q], 0.f);
        *(half4*)(dst + (((size_t)b * LSEQ + l) << 8) + co) = o;
      }
    }
  }
}

// x[16][1][8192] -> h0[b][l][co] (f16) = relu(conv1d_{1->256}(x) + b_in)
__global__ void conv_in_kernel(const float* __restrict__ x, const float* __restrict__ w_in,
                               const float* __restrict__ b_in, _Float16* __restrict__ hout) {
  size_t idx = (size_t)blockIdx.x * blockDim.x + threadIdx.x;
  int co = (int)(idx & 255);
  size_t pos = idx >> 8;
  int l = (int)(pos & (LSEQ - 1));
  int b = (int)(pos >> 13);
  float acc = b_in[co];
#pragma unroll
  for (int k = 0; k < 3; ++k) {
    int lg = l + k - 1;
    if (lg >= 0 && lg < LSEQ) acc += w_in[co * 3 + k] * x[(size_t)b * LSEQ + lg];
  }
  hout[idx] = (_Float16)fmaxf(acc, 0.f);
}

// final conv 256->4 + bias + relu + pixel-shuffle: out[b][l*4+co]
__global__ __launch_bounds__(256) void conv_u2_kernel(
    const _Float16* __restrict__ hin, const float* __restrict__ w2T4 /*[tap][ci][4]*/,
    const float* __restrict__ b_u2, float* __restrict__ out) {
  const size_t idx = (size_t)blockIdx.x * 256 + threadIdx.x;  // = b*8192 + l
  const int l = (int)(idx & (LSEQ - 1));
  const int b = (int)(idx >> 13);
  floatx4 acc = *(const floatx4*)b_u2;
  for (int tap = 0; tap < 3; ++tap) {
    const int lg = l + tap - 1;
    if (lg < 0 || lg >= LSEQ) continue;
    const half8* hp = (const half8*)(hin + (((size_t)b * LSEQ + lg) << 8));
    const floatx4* wp = (const floatx4*)(w2T4 + tap * 1024);
    for (int q = 0; q < 32; ++q) {
      half8 hv = hp[q];
#pragma unroll
      for (int r = 0; r < 8; ++r) {
        floatx4 wv = wp[q * 8 + r];
        float h = (float)hv[r];
        acc[0] += h * wv[0]; acc[1] += h * wv[1]; acc[2] += h * wv[2]; acc[3] += h * wv[3];
      }
    }
  }
  floatx4 y;
#pragma unroll
  for (int r = 0; r < 4; ++r) y[r] = fmaxf(acc[r], 0.f);
  *(floatx4*)(out + ((size_t)b << 15) + (size_t)l * 4) = y;
}

// weight transforms (DENSE layout) + BN folding
__global__ void prep_kernel(
    const float* __restrict__ w_r1, const float* __restrict__ w_r2,
    const float* __restrict__ w_u1, const float* __restrict__ w_u2,
    const float* __restrict__ b_r1, const float* __restrict__ g1,
    const float* __restrict__ be1, const float* __restrict__ m1, const float* __restrict__ v1,
    const float* __restrict__ b_r2, const float* __restrict__ g2,
    const float* __restrict__ be2, const float* __restrict__ m2, const float* __restrict__ v2,
    const float* __restrict__ b_u1,
    _Float16* __restrict__ wT1, _Float16* __restrict__ wT2, _Float16* __restrict__ wTu1,
    float* __restrict__ wu2T4,
    float* __restrict__ sc1, float* __restrict__ sh1,
    float* __restrict__ sc2, float* __restrict__ sh2,
    float* __restrict__ scu1, float* __restrict__ shu1) {
  int idx = blockIdx.x * blockDim.x + threadIdx.x;
  if (idx < 3 * CCH * CCH) {
    // dense dst layout [tap][kc][co][32]: idx = ((tap*8+kc)*256+co)*32+c
    int tap = idx >> 16;               // / 65536
    int rem = idx & 65535;
    int kc = rem >> 13;                // / 8192
    int rem2 = rem & 8191;
    int co = rem2 >> 5, c = rem2 & 31;
    int ci = kc * 32 + c;
    size_t s = ((size_t)co * CCH + ci) * 3 + tap;
    wT1[idx] = (_Float16)w_r1[s];
    wT2[idx] = (_Float16)w_r2[s];
    wTu1[idx] = (_Float16)w_u1[s];
  }
  if (idx < 3 * CCH * 4) {  // wu2T4[tap][ci][co]
    int co = idx & 3;
    int ci = (idx >> 2) & 255;
    int tap = idx >> 10;
    wu2T4[idx] = w_u2[((size_t)co * CCH + ci) * 3 + tap];
  }
  if (idx < CCH) {
    float s1 = g1[idx] * rsqrtf(v1[idx] + 1e-5f);
    sc1[idx] = s1;
    sh1[idx] = (b_r1[idx] - m1[idx]) * s1 + be1[idx];
    float s2 = g2[idx] * rsqrtf(v2[idx] + 1e-5f);
    sc2[idx] = s2;
    sh2[idx] = (b_r2[idx] - m2[idx]) * s2 + be2[idx];
    scu1[idx] = 1.f;
    shu1[idx] = b_u1[idx];
  }
}

__global__ void diag_kernel(float* out, float v) { out[0] = v; }

extern "C" void kernel_launch(void* const* d_in, const int* in_sizes, int n_in,
                              void* d_out, int out_size, void* d_ws, size_t ws_size,
                              hipStream_t stream) {
  (void)in_sizes; (void)n_in; (void)out_size;
  const size_t HELEMS = (size_t)16 * LSEQ * CCH;      // 33,554,432
  const size_t HB = HELEMS * sizeof(_Float16);        // 67,108,864
  const size_t NEED = 2 * HB + 2u * 1024 * 1024;      // ~136 MiB
  if (ws_size < NEED) {
    diag_kernel<<<1, 1, 0, stream>>>((float*)d_out, 1000.0f + (float)(ws_size >> 20));
    return;
  }
  const float* x    = (const float*)d_in[0];
  const float* w_in = (const float*)d_in[3];
  const float* b_in = (const float*)d_in[4];
  const float* w_r1 = (const float*)d_in[5];
  const float* b_r1 = (const float*)d_in[6];
  const float* g1   = (const float*)d_in[7];
  const float* be1  = (const float*)d_in[8];
  const float* m1   = (const float*)d_in[9];
  const float* v1   = (const float*)d_in[10];
  const float* w_r2 = (const float*)d_in[11];
  const float* b_r2 = (const float*)d_in[12];
  const float* g2   = (const float*)d_in[13];
  const float* be2  = (const float*)d_in[14];
  const float* m2   = (const float*)d_in[15];
  const float* v2   = (const float*)d_in[16];
  const float* w_u1 = (const float*)d_in[17];
  const float* b_u1 = (const float*)d_in[18];
  const float* w_u2 = (const float*)d_in[19];
  const float* b_u2 = (const float*)d_in[20];

  char* ws = (char*)d_ws;
  _Float16* buf0 = (_Float16*)ws;
  _Float16* buf1 = (_Float16*)(ws + HB);
  _Float16* wT1  = (_Float16*)(ws + 2 * HB);
  _Float16* wT2  = wT1 + 3 * CCH * CCH;
  _Float16* wTu1 = wT2 + 3 * CCH * CCH;
  float* sc1  = (float*)(wTu1 + 3 * CCH * CCH);
  float* sh1  = sc1 + CCH;
  float* sc2  = sh1 + CCH;
  float* sh2  = sc2 + CCH;
  float* scu1 = sh2 + CCH;
  float* shu1 = scu1 + CCH;
  float* wu2T4 = shu1 + CCH;

  prep_kernel<<<768, 256, 0, stream>>>(w_r1, w_r2, w_u1, w_u2, b_r1, g1, be1, m1, v1,
                                       b_r2, g2, be2, m2, v2, b_u1,
                                       wT1, wT2, wTu1, wu2T4, sc1, sh1, sc2, sh2, scu1, shu1);
  conv_in_kernel<<<131072, 256, 0, stream>>>(x, w_in, b_in, buf0);
  const int grid = 16 * NT;  // 1024
  for (int k = 0; k < 32; ++k) {
    const _Float16* s = (k & 1) ? buf1 : buf0;
    _Float16* d = (k & 1) ? buf0 : buf1;
    res2<0><<<grid, 512, 0, stream>>>(s, d, wT1, wT2, sc1, sh1, sc2, sh2);
  }
  // state in buf0 after 32 resblocks
  res2<1><<<grid, 512, 0, stream>>>(buf0, buf1, wTu1, (const _Float16*)nullptr,
                                    scu1, shu1, (const float*)nullptr, (const float*)nullptr);
  conv_u2_kernel<<<512, 256, 0, stream>>>(buf1, wu2T4, b_u2, (float*)d_out);
}